// Round 9
// baseline (1043.185 us; speedup 1.0000x reference)
//
#include <hip/hip_runtime.h>
#include <math.h>

// Problem constants
#define BB 64
#define LL 24
#define DD 512
#define GG 2560        // 5*H
#define NSTEP 23       // LL-1
#define NBLK 256       // cooperative grid (1 block/CU, proven resident)
#define NTILES 160     // phase-B n-tiles: 5120/32, full-K per tile

__device__ __forceinline__ float sigm(float x) { return 1.0f / (1.0f + __expf(-x)); }

// ---------------------------------------------------------------------------
// Agent-scope (sc1) relaxed access helpers — cross-XCD coherent, NO cache
// maintenance (R5 lesson: acquire/release fences flush/invalidate L2).
// ---------------------------------------------------------------------------
__device__ __forceinline__ void stf2(float* p, float a, float b) {
    union { float f[2]; unsigned long long u; } x;
    x.f[0] = a; x.f[1] = b;
    __hip_atomic_store((unsigned long long*)p, x.u, __ATOMIC_RELAXED, __HIP_MEMORY_SCOPE_AGENT);
}
__device__ __forceinline__ float2 ldf2(const float* p) {
    union { float f[2]; unsigned long long u; } x;
    x.u = __hip_atomic_load((unsigned long long*)p, __ATOMIC_RELAXED, __HIP_MEMORY_SCOPE_AGENT);
    return make_float2(x.f[0], x.f[1]);
}
__device__ __forceinline__ void stf(float* p, float v) {
    __hip_atomic_store(p, v, __ATOMIC_RELAXED, __HIP_MEMORY_SCOPE_AGENT);
}
__device__ __forceinline__ float ldf(const float* p) {
    return __hip_atomic_load((float*)p, __ATOMIC_RELAXED, __HIP_MEMORY_SCOPE_AGENT);
}
__device__ __forceinline__ void sti(int* p, int v) {
    __hip_atomic_store(p, v, __ATOMIC_RELAXED, __HIP_MEMORY_SCOPE_AGENT);
}
__device__ __forceinline__ int ldi(const int* p) {
    return __hip_atomic_load((int*)p, __ATOMIC_RELAXED, __HIP_MEMORY_SCOPE_AGENT);
}
__device__ __forceinline__ void drain_stores() {
    asm volatile("s_waitcnt vmcnt(0)" ::: "memory");
}

// ---------------------------------------------------------------------------
// Hang-proof leaf-counter grid barrier (R8 post-mortem). NO release stage:
// arrival = fetch_add on leaf[bid&7] (8 padded lines, monotone, never reset);
// wait = wave 0 polls all 8 leaves in ONE vector load (lane j < 8 watches
// leaf j) until all >= 32*ep. Completion is derivable purely from arrival
// state -> nothing to propagate, nothing to lose. Max ep 45 -> 1440, no wrap.
// ---------------------------------------------------------------------------
__device__ __forceinline__ void gbar(int* __restrict__ bar, int ep) {
    __syncthreads();  // each wave drains its vmem (compiler emits vmcnt(0))
    if (threadIdx.x < 64) {
        if (threadIdx.x == 0) {
            drain_stores();
            (void)__hip_atomic_fetch_add(bar + (blockIdx.x & 7) * 16, 1, __ATOMIC_RELAXED,
                                         __HIP_MEMORY_SCOPE_AGENT);
        }
        const int target = ep * 32;
        bool done = false;
        while (!done) {
            int v = (threadIdx.x < 8) ? ldi(bar + threadIdx.x * 16) : target;
            done = __all(v >= target);
            if (!done) __builtin_amdgcn_s_sleep(2);
        }
    }
    __syncthreads();
}

__global__ void init_k(int* __restrict__ bar) {
    int tid = threadIdx.x;
    if (tid < 512) bar[tid] = 0;
}

// ---------------------------------------------------------------------------
// fp32 GEMM, 64x128 tile. C[m][n] = sum_k A[m][k]*W[n][k] (+bias).
// MODE 0 = WORD (W 1024x512 row-major, bias, out h|c split at n=512)
// MODE 1 = AB0  (W = comp_W halves at n=2560)
// ---------------------------------------------------------------------------
template <int MODE>
__global__ __launch_bounds__(256) void gemm64(const float* __restrict__ A,
                                              const float* __restrict__ Wt,
                                              const float* __restrict__ bias,
                                              float* __restrict__ O0,
                                              float* __restrict__ O1) {
    __shared__ float As[16][68];
    __shared__ float Bs[16][132];
    const int tid = threadIdx.x;
    const int n0 = blockIdx.x * 128;
    const int m0 = blockIdx.y * 64;
    const int tn = tid & 15;
    const int tm = tid >> 4;

    float acc[4][8];
#pragma unroll
    for (int y = 0; y < 4; ++y)
#pragma unroll
        for (int x = 0; x < 8; ++x) acc[y][x] = 0.f;

    for (int kt = 0; kt < 512; kt += 16) {
        {
            int r = tid >> 2, c4 = tid & 3;
            float4 v = *(const float4*)(A + (size_t)(m0 + r) * DD + kt + c4 * 4);
            As[c4 * 4 + 0][r] = v.x;
            As[c4 * 4 + 1][r] = v.y;
            As[c4 * 4 + 2][r] = v.z;
            As[c4 * 4 + 3][r] = v.w;
        }
#pragma unroll
        for (int ii = 0; ii < 2; ++ii) {
            int idx = tid + ii * 256;
            int r = idx >> 2, c4 = idx & 3;
            int n = n0 + r;
            const float* wrow;
            if constexpr (MODE == 0) {
                wrow = Wt + (size_t)n * DD;
            } else {
                wrow = (n < GG) ? (Wt + (size_t)n * (2 * DD))
                                : (Wt + (size_t)(n - GG) * (2 * DD) + DD);
            }
            float4 v = *(const float4*)(wrow + kt + c4 * 4);
            Bs[c4 * 4 + 0][r] = v.x;
            Bs[c4 * 4 + 1][r] = v.y;
            Bs[c4 * 4 + 2][r] = v.z;
            Bs[c4 * 4 + 3][r] = v.w;
        }
        __syncthreads();
#pragma unroll
        for (int k = 0; k < 16; ++k) {
            float4 a = *(const float4*)&As[k][tm * 4];
            float4 b0 = *(const float4*)&Bs[k][tn * 4];
            float4 b1 = *(const float4*)&Bs[k][64 + tn * 4];
            float av[4] = {a.x, a.y, a.z, a.w};
            float bv[8] = {b0.x, b0.y, b0.z, b0.w, b1.x, b1.y, b1.z, b1.w};
#pragma unroll
            for (int y = 0; y < 4; ++y)
#pragma unroll
                for (int x = 0; x < 8; ++x) acc[y][x] += av[y] * bv[x];
        }
        __syncthreads();
    }

#pragma unroll
    for (int y = 0; y < 4; ++y) {
        const int m = m0 + tm * 4 + y;
#pragma unroll
        for (int g = 0; g < 2; ++g) {
            int n = n0 + g * 64 + tn * 4;
            float4 v;
            v.x = acc[y][g * 4 + 0];
            v.y = acc[y][g * 4 + 1];
            v.z = acc[y][g * 4 + 2];
            v.w = acc[y][g * 4 + 3];
            float* dst;
            if constexpr (MODE == 0) {
                v.x += bias[n + 0];
                v.y += bias[n + 1];
                v.z += bias[n + 2];
                v.w += bias[n + 3];
                dst = (n < DD) ? (O0 + (size_t)m * DD + n) : (O1 + (size_t)m * DD + (n - DD));
            } else {
                dst = (n < GG) ? (O0 + (size_t)m * GG + n) : (O1 + (size_t)m * GG + (n - GG));
            }
            *(float4*)dst = v;
        }
    }
}

// ---------------------------------------------------------------------------
// pre-phase scorer (normal cached loads; operands from previous dispatches)
// ---------------------------------------------------------------------------
__device__ __forceinline__ float half_dot(const float* __restrict__ ar,
                                          const float* __restrict__ br,
                                          const float* __restrict__ cb,
                                          const float* __restrict__ cl,
                                          const float* __restrict__ cr,
                                          const float* __restrict__ q, int lane) {
    float part = 0.f;
#pragma unroll
    for (int d = lane; d < DD; d += 128) {
        float gi = ar[d] + br[d] + cb[d];
        float gfl = ar[DD + d] + br[DD + d] + cb[DD + d];
        float gfr = ar[2 * DD + d] + br[2 * DD + d] + cb[2 * DD + d];
        float gu = ar[3 * DD + d] + br[3 * DD + d] + cb[3 * DD + d];
        float go = ar[4 * DD + d] + br[4 * DD + d] + cb[4 * DD + d];
        float nc = cl[d] * sigm(gfl + 1.f) + cr[d] * sigm(gfr + 1.f) + tanhf(gu) * sigm(gi);
        part += sigm(go) * tanhf(nc) * q[d];
    }
#pragma unroll
    for (int off = 32; off; off >>= 1) part += __shfl_down(part, off);
    return part;
}

// ---------------------------------------------------------------------------
// sc1 gate pair for dims d, d+1 (a/b rows coherent; rest cached)
// ---------------------------------------------------------------------------
__device__ __forceinline__ void gate2(const float* ar, const float* br,
                                      const float* __restrict__ cb,
                                      const float* __restrict__ cl,
                                      const float* __restrict__ cr, int d,
                                      float nh[2], float nc[2]) {
    float2 A0 = ldf2(ar + d),          B0 = ldf2(br + d);
    float2 A1 = ldf2(ar + DD + d),     B1 = ldf2(br + DD + d);
    float2 A2 = ldf2(ar + 2 * DD + d), B2 = ldf2(br + 2 * DD + d);
    float2 A3 = ldf2(ar + 3 * DD + d), B3 = ldf2(br + 3 * DD + d);
    float2 A4 = ldf2(ar + 4 * DD + d), B4 = ldf2(br + 4 * DD + d);
    float2 C0 = *(const float2*)(cb + d);
    float2 C1 = *(const float2*)(cb + DD + d);
    float2 C2 = *(const float2*)(cb + 2 * DD + d);
    float2 C3 = *(const float2*)(cb + 3 * DD + d);
    float2 C4 = *(const float2*)(cb + 4 * DD + d);
    float2 CL = *(const float2*)(cl + d);
    float2 CR = *(const float2*)(cr + d);
    float gi0 = A0.x + B0.x + C0.x, gi1 = A0.y + B0.y + C0.y;
    float gfl0 = A1.x + B1.x + C1.x, gfl1 = A1.y + B1.y + C1.y;
    float gfr0 = A2.x + B2.x + C2.x, gfr1 = A2.y + B2.y + C2.y;
    float gu0 = A3.x + B3.x + C3.x, gu1 = A3.y + B3.y + C3.y;
    float go0 = A4.x + B4.x + C4.x, go1 = A4.y + B4.y + C4.y;
    nc[0] = CL.x * sigm(gfl0 + 1.f) + CR.x * sigm(gfr0 + 1.f) + tanhf(gu0) * sigm(gi0);
    nc[1] = CL.y * sigm(gfl1 + 1.f) + CR.y * sigm(gfr1 + 1.f) + tanhf(gu1) * sigm(gi1);
    nh[0] = sigm(go0) * tanhf(nc[0]);
    nh[1] = sigm(go1) * tanhf(nc[1]);
}

// ---------------------------------------------------------------------------
// Persistent kernel: pre-scores + 23 merge steps. Structure as R7; leaf
// barrier and conflict-free phase-B staging maps are the changes.
// ---------------------------------------------------------------------------
__global__ __launch_bounds__(256, 2) void loop_k(
    const int* __restrict__ length, float* __restrict__ cbuf, float* __restrict__ acache,
    float* __restrict__ bcache, float* __restrict__ hm, float* __restrict__ hout,
    float* __restrict__ scores_g, int* __restrict__ msel, const float* __restrict__ comp_W,
    const float* __restrict__ compb, const float* __restrict__ q, float* __restrict__ out,
    int* __restrict__ bar) {
    __shared__ float As[128][68];   // phase-B A chunk (k-major)
    __shared__ float Bs[128][36];   // phase-B W chunk
    __shared__ float red_s[4];
    __shared__ float sc_l[32];
    __shared__ int seq_l[32];
    __shared__ int k_sh;
    __shared__ int msel_s[BB];

    const int tid = threadIdx.x;
    const int bid = blockIdx.x;
    const int b = bid;
    const bool amA = bid < BB;
    const int half = tid >> 7;
    const int lane7 = tid & 127;

    int maxlen = 0;
    for (int j = 0; j < BB; ++j) maxlen = max(maxlen, length[j]);
    int lenb = 0, kp = 0;
    if (amA) lenb = length[b];

    // phase-B roles (conflict-free staging maps; R7 had 4/8-way write conflicts)
    const int ar_ = tid & 63, aks = tid >> 6;   // A: row=lane (2-way free), k-slice
    const int wnl = tid & 31, wkg = tid >> 5;   // B: row=lane%32, k-slice
    const float* wrow = nullptr;
    if (bid < NTILES) {
        int n = bid * 32 + wnl;
        wrow = (n < GG) ? (comp_W + (size_t)n * (2 * DD))
                        : (comp_W + (size_t)(n - GG) * (2 * DD) + DD);
    }

    // ---- pre-phase: 23x64 initial candidate scores (512 half-block tasks) ---
    for (int it = 0; it < 3; ++it) {
        int c = it * (2 * NBLK) + bid * 2 + half;
        bool valid = c < BB * NSTEP;
        float w = 0.f;
        if (valid) {
            int cb_ = c / NSTEP, cp = c % NSTEP;
            w = half_dot(acache + (size_t)(cb_ * LL + cp) * GG,
                         bcache + (size_t)(cb_ * LL + cp + 1) * GG, compb,
                         cbuf + (size_t)(cb_ * LL + cp) * DD,
                         cbuf + (size_t)(cb_ * LL + cp + 1) * DD, q, lane7);
        }
        if ((tid & 63) == 0) red_s[tid >> 6] = w;
        __syncthreads();
        if ((tid == 0 || tid == 128) && valid) {
            int base = (tid >> 6);
            stf(&scores_g[c], red_s[base] + red_s[base + 1]);
        }
        __syncthreads();
    }
    int ep = 0;
    gbar(bar, ++ep);

    if (amA) {
        if (tid < NSTEP) sc_l[tid] = ldf(&scores_g[b * NSTEP + tid]);
        if (tid < LL) seq_l[tid] = tid;
    }
    __syncthreads();

    const int imax = min(NSTEP, maxlen - 1);
    for (int i = 0; i < imax; ++i) {
        // ---------------- phase A (blocks 0..63) ----------------
        if (amA) {
            const int ncand = NSTEP - i;
            if (i > 0 && i < lenb) {
                int p = (tid < 128) ? (kp - 1) : kp;
                bool valid = (p >= 0) && (p < ncand);
                float w = 0.f;
                if (valid) {
                    int sl = seq_l[p], sr = seq_l[p + 1];
                    const float* ar = acache + (size_t)(b * LL + sl) * GG;
                    const float* br = bcache + (size_t)(b * LL + sr) * GG;
                    const float* cl = cbuf + (size_t)(b * LL + sl) * DD;
                    const float* cr = cbuf + (size_t)(b * LL + sr) * DD;
#pragma unroll
                    for (int pass = 0; pass < 2; ++pass) {
                        int d = pass * 256 + lane7 * 2;
                        float nh[2], nc[2];
                        gate2(ar, br, compb, cl, cr, d, nh, nc);
                        float2 Q = *(const float2*)(q + d);
                        w += nh[0] * Q.x + nh[1] * Q.y;
                    }
#pragma unroll
                    for (int off = 32; off; off >>= 1) w += __shfl_down(w, off);
                }
                if ((tid & 63) == 0) red_s[tid >> 6] = w;
                __syncthreads();
                if (tid == 0) {
                    if (kp - 1 >= 0) sc_l[kp - 1] = red_s[0] + red_s[1];
                    if (kp < ncand) sc_l[kp] = red_s[2] + red_s[3];
                }
                __syncthreads();
            }
            if (i + 1 < lenb) {
                if (tid == 0) {
                    const int vmax = lenb - i - 2;
                    int k = 0;
                    float best = sc_l[0];
                    for (int pp = 1; pp <= vmax; ++pp)
                        if (sc_l[pp] > best) { best = sc_l[pp]; k = pp; }
                    k_sh = k;
                }
                __syncthreads();
                const int k = k_sh;
                const int sl = seq_l[k], sr = seq_l[k + 1];
                const float* ar = acache + (size_t)(b * LL + sl) * GG;
                const float* br = bcache + (size_t)(b * LL + sr) * GG;
                const float* cl = cbuf + (size_t)(b * LL + sl) * DD;
                const float* cr = cbuf + (size_t)(b * LL + sr) * DD;
                {
                    const int d = 2 * tid;
                    float nh[2], nc[2];
                    gate2(ar, br, compb, cl, cr, d, nh, nc);
                    *(float2*)(cbuf + (size_t)(b * LL + sl) * DD + d) =
                        make_float2(nc[0], nc[1]);
                    *(float2*)(hout + (size_t)b * DD + d) = make_float2(nh[0], nh[1]);
                    stf2(hm + ((size_t)i * BB + b) * DD + d, nh[0], nh[1]);
                }
                float sv = (tid + 1 < ncand) ? sc_l[tid + 1] : 0.f;
                int qv = (tid + 1 < LL - i) ? seq_l[tid + 1] : 0;
                __syncthreads();
                if (tid >= k + 1 && tid <= ncand - 2) sc_l[tid] = sv;
                if (tid >= k + 1 && tid <= LL - i - 2) seq_l[tid] = qv;
                if (tid == 0) sti(&msel[b], sl);
                kp = k;
            } else {
                const int d = 2 * tid;
                float2 v = *(const float2*)(hout + (size_t)b * DD + d);
                stf2(hm + ((size_t)i * BB + b) * DD + d, v.x, v.y);
            }
        }
        // ---------------- phase B (blocks 0..159) ----------------
        if (i < imax - 1) {
            float4 rw[4];
            if (bid < NTILES) {  // W prefetch is input-stable: legal pre-barrier
#pragma unroll
                for (int j = 0; j < 4; ++j) rw[j] = *(const float4*)(wrow + wkg * 16 + j * 4);
            }
            gbar(bar, ++ep);
            if (tid < BB) msel_s[tid] = ldi(&msel[tid]);
            __syncthreads();
            if (bid < NTILES) {
                const int n0 = bid * 32;
                const int tn = tid & 15, tm = tid >> 4;
                const float* hmi = hm + (size_t)i * BB * DD;
                const float* arow = hmi + (size_t)ar_ * DD;
                float acc[4][2];
#pragma unroll
                for (int y = 0; y < 4; ++y) { acc[y][0] = 0.f; acc[y][1] = 0.f; }
                float4 ra[8];
#pragma unroll
                for (int j = 0; j < 8; ++j) ra[j] = *(const float4*)(arow + aks * 32 + j * 4);
#pragma unroll
                for (int c = 0; c < 4; ++c) {
                    __syncthreads();
#pragma unroll
                    for (int j = 0; j < 8; ++j) {
                        int kl = aks * 32 + j * 4;
                        As[kl + 0][ar_] = ra[j].x;
                        As[kl + 1][ar_] = ra[j].y;
                        As[kl + 2][ar_] = ra[j].z;
                        As[kl + 3][ar_] = ra[j].w;
                    }
#pragma unroll
                    for (int j = 0; j < 4; ++j) {
                        int kl = wkg * 16 + j * 4;
                        Bs[kl + 0][wnl] = rw[j].x;
                        Bs[kl + 1][wnl] = rw[j].y;
                        Bs[kl + 2][wnl] = rw[j].z;
                        Bs[kl + 3][wnl] = rw[j].w;
                    }
                    if (c < 3) {
                        int kb = (c + 1) * 128;
#pragma unroll
                        for (int j = 0; j < 8; ++j)
                            ra[j] = *(const float4*)(arow + kb + aks * 32 + j * 4);
#pragma unroll
                        for (int j = 0; j < 4; ++j)
                            rw[j] = *(const float4*)(wrow + kb + wkg * 16 + j * 4);
                    }
                    __syncthreads();
#pragma unroll 8
                    for (int k = 0; k < 128; ++k) {
                        float4 a = *(const float4*)&As[k][tm * 4];
                        float2 w = *(const float2*)&Bs[k][tn * 2];
                        acc[0][0] += a.x * w.x; acc[0][1] += a.x * w.y;
                        acc[1][0] += a.y * w.x; acc[1][1] += a.y * w.y;
                        acc[2][0] += a.z * w.x; acc[2][1] += a.z * w.y;
                        acc[3][0] += a.w * w.x; acc[3][1] += a.w * w.y;
                    }
                }
                const int n = n0 + tn * 2;
#pragma unroll
                for (int y = 0; y < 4; ++y) {
                    int m = tm * 4 + y;
                    size_t row = (size_t)(m * LL + msel_s[m]);
                    if (n < GG) stf2(acache + row * GG + n, acc[y][0], acc[y][1]);
                    else stf2(bcache + row * GG + (n - GG), acc[y][0], acc[y][1]);
                }
            }
            gbar(bar, ++ep);
        }
    }

    if (amA) {
        const int d = 2 * tid;
        *(float2*)(out + (size_t)b * DD + d) = *(const float2*)(hout + (size_t)b * DD + d);
    }
}

// ---------------------------------------------------------------------------
extern "C" void kernel_launch(void* const* d_in, const int* in_sizes, int n_in, void* d_out,
                              int out_size, void* d_ws, size_t ws_size, hipStream_t stream) {
    const float* inp = (const float*)d_in[0];
    const int* length = (const int*)d_in[1];
    const float* word_W = (const float*)d_in[2];
    const float* word_b = (const float*)d_in[3];
    const float* comp_W = (const float*)d_in[4];
    const float* comp_b = (const float*)d_in[5];
    const float* comp_q = (const float*)d_in[6];
    float* out = (float*)d_out;

    float* ws = (float*)d_ws;
    size_t off = 0;
    float* hbuf = ws + off;   off += (size_t)BB * LL * DD;
    float* cbuf = ws + off;   off += (size_t)BB * LL * DD;
    float* acache = ws + off; off += (size_t)BB * LL * GG;
    float* bcache = ws + off; off += (size_t)BB * LL * GG;
    float* hm = ws + off;     off += (size_t)NSTEP * BB * DD;
    float* hout = ws + off;   off += (size_t)BB * DD;
    float* scores = ws + off; off += 2048;
    int* msel = (int*)(ws + off); off += 64;
    int* bar = (int*)(ws + off);  off += 512;
    (void)ws_size; (void)in_sizes; (void)n_in; (void)out_size;

    init_k<<<1, 512, 0, stream>>>(bar);

    // word projection: h,c = split(inp @ word_W.T + word_b)   (192 blocks)
    gemm64<0><<<dim3(8, 24), 256, 0, stream>>>(inp, word_W, word_b, hbuf, cbuf);

    // a/b caches for all 1536 items                            (960 blocks)
    gemm64<1><<<dim3(40, 24), 256, 0, stream>>>(hbuf, comp_W, nullptr, acache, bcache);

    // persistent kernel: pre-scores + all merge steps
    const int* a0 = length;
    float* a1 = cbuf; float* a2 = acache; float* a3 = bcache; float* a4 = hm;
    float* a5 = hout; float* a6 = scores; int* a7 = msel;
    const float* a8 = comp_W; const float* a9 = comp_b; const float* a10 = comp_q;
    float* a11 = out; int* a12 = bar;
    void* args[] = {&a0, &a1, &a2, &a3, &a4, &a5, &a6, &a7, &a8, &a9, &a10, &a11, &a12};
    hipError_t err = hipLaunchCooperativeKernel(reinterpret_cast<void*>(loop_k), dim3(NBLK),
                                                dim3(256), args, 0, stream);
    (void)err;
}

// Round 10
// 1003.891 us; speedup vs baseline: 1.0391x; 1.0391x over previous
//
#include <hip/hip_runtime.h>
#include <math.h>

// Problem constants
#define BB 64
#define LL 24
#define DD 512
#define GG 2560        // 5*H
#define NSTEP 23       // LL-1
#define NBLK 256       // cooperative grid (1 block/CU, proven resident)
#define NTILES 160     // phase-B n-tiles: 5120/32, full-K per tile
#define BARLINE 16     // ints per padded counter line

__device__ __forceinline__ float sigm(float x) { return 1.0f / (1.0f + __expf(-x)); }

// ---------------------------------------------------------------------------
// Agent-scope (sc1) relaxed access helpers — cross-XCD coherent, NO cache
// maintenance (R5 lesson: acquire/release fences flush/invalidate L2).
// ---------------------------------------------------------------------------
__device__ __forceinline__ void stf2(float* p, float a, float b) {
    union { float f[2]; unsigned long long u; } x;
    x.f[0] = a; x.f[1] = b;
    __hip_atomic_store((unsigned long long*)p, x.u, __ATOMIC_RELAXED, __HIP_MEMORY_SCOPE_AGENT);
}
__device__ __forceinline__ float2 ldf2(const float* p) {
    union { float f[2]; unsigned long long u; } x;
    x.u = __hip_atomic_load((unsigned long long*)p, __ATOMIC_RELAXED, __HIP_MEMORY_SCOPE_AGENT);
    return make_float2(x.f[0], x.f[1]);
}
__device__ __forceinline__ void stf(float* p, float v) {
    __hip_atomic_store(p, v, __ATOMIC_RELAXED, __HIP_MEMORY_SCOPE_AGENT);
}
__device__ __forceinline__ float ldf(const float* p) {
    return __hip_atomic_load((float*)p, __ATOMIC_RELAXED, __HIP_MEMORY_SCOPE_AGENT);
}
__device__ __forceinline__ void sti(int* p, int v) {
    __hip_atomic_store(p, v, __ATOMIC_RELAXED, __HIP_MEMORY_SCOPE_AGENT);
}
__device__ __forceinline__ int ldi(const int* p) {
    return __hip_atomic_load((int*)p, __ATOMIC_RELAXED, __HIP_MEMORY_SCOPE_AGENT);
}
__device__ __forceinline__ void drain_stores() {
    asm volatile("s_waitcnt vmcnt(0)" ::: "memory");
}

// ---------------------------------------------------------------------------
// Per-step dataflow sync (R10): producers fetch_add a monotone per-step
// counter line AFTER draining stores; consumers poll only the counters they
// depend on. Single hop: arrival IS the release. Bounded sleep escalation
// prevents the R9 31ms spin pathology.
// ---------------------------------------------------------------------------
__device__ __forceinline__ void arrive_cnt(int* line) {
    if (threadIdx.x == 0) {
        drain_stores();
        (void)__hip_atomic_fetch_add(line, 1, __ATOMIC_RELAXED, __HIP_MEMORY_SCOPE_AGENT);
    }
}
template <int NL>
__device__ __forceinline__ void wait_lines(const int* base, int tgt) {
    if (threadIdx.x < 64) {
        int spins = 0;
        bool done = false;
        while (!done) {
            int v = (threadIdx.x < NL) ? ldi(base + threadIdx.x * BARLINE) : tgt;
            done = __all(v >= tgt);
            if (!done && ++spins > 512) __builtin_amdgcn_s_sleep(8);
        }
    }
    __syncthreads();
}

__global__ void init_k(int* __restrict__ bar) {
    for (int idx = threadIdx.x; idx < 2560; idx += 256) bar[idx] = 0;
}

// ---------------------------------------------------------------------------
// fp32 GEMM, 64x128 tile. C[m][n] = sum_k A[m][k]*W[n][k] (+bias).
// MODE 0 = WORD (W 1024x512 row-major, bias, out h|c split at n=512)
// MODE 1 = AB0  (W = comp_W halves at n=2560)
// ---------------------------------------------------------------------------
template <int MODE>
__global__ __launch_bounds__(256) void gemm64(const float* __restrict__ A,
                                              const float* __restrict__ Wt,
                                              const float* __restrict__ bias,
                                              float* __restrict__ O0,
                                              float* __restrict__ O1) {
    __shared__ float As[16][68];
    __shared__ float Bs[16][132];
    const int tid = threadIdx.x;
    const int n0 = blockIdx.x * 128;
    const int m0 = blockIdx.y * 64;
    const int tn = tid & 15;
    const int tm = tid >> 4;

    float acc[4][8];
#pragma unroll
    for (int y = 0; y < 4; ++y)
#pragma unroll
        for (int x = 0; x < 8; ++x) acc[y][x] = 0.f;

    for (int kt = 0; kt < 512; kt += 16) {
        {
            int r = tid >> 2, c4 = tid & 3;
            float4 v = *(const float4*)(A + (size_t)(m0 + r) * DD + kt + c4 * 4);
            As[c4 * 4 + 0][r] = v.x;
            As[c4 * 4 + 1][r] = v.y;
            As[c4 * 4 + 2][r] = v.z;
            As[c4 * 4 + 3][r] = v.w;
        }
#pragma unroll
        for (int ii = 0; ii < 2; ++ii) {
            int idx = tid + ii * 256;
            int r = idx >> 2, c4 = idx & 3;
            int n = n0 + r;
            const float* wrow;
            if constexpr (MODE == 0) {
                wrow = Wt + (size_t)n * DD;
            } else {
                wrow = (n < GG) ? (Wt + (size_t)n * (2 * DD))
                                : (Wt + (size_t)(n - GG) * (2 * DD) + DD);
            }
            float4 v = *(const float4*)(wrow + kt + c4 * 4);
            Bs[c4 * 4 + 0][r] = v.x;
            Bs[c4 * 4 + 1][r] = v.y;
            Bs[c4 * 4 + 2][r] = v.z;
            Bs[c4 * 4 + 3][r] = v.w;
        }
        __syncthreads();
#pragma unroll
        for (int k = 0; k < 16; ++k) {
            float4 a = *(const float4*)&As[k][tm * 4];
            float4 b0 = *(const float4*)&Bs[k][tn * 4];
            float4 b1 = *(const float4*)&Bs[k][64 + tn * 4];
            float av[4] = {a.x, a.y, a.z, a.w};
            float bv[8] = {b0.x, b0.y, b0.z, b0.w, b1.x, b1.y, b1.z, b1.w};
#pragma unroll
            for (int y = 0; y < 4; ++y)
#pragma unroll
                for (int x = 0; x < 8; ++x) acc[y][x] += av[y] * bv[x];
        }
        __syncthreads();
    }

#pragma unroll
    for (int y = 0; y < 4; ++y) {
        const int m = m0 + tm * 4 + y;
#pragma unroll
        for (int g = 0; g < 2; ++g) {
            int n = n0 + g * 64 + tn * 4;
            float4 v;
            v.x = acc[y][g * 4 + 0];
            v.y = acc[y][g * 4 + 1];
            v.z = acc[y][g * 4 + 2];
            v.w = acc[y][g * 4 + 3];
            float* dst;
            if constexpr (MODE == 0) {
                v.x += bias[n + 0];
                v.y += bias[n + 1];
                v.z += bias[n + 2];
                v.w += bias[n + 3];
                dst = (n < DD) ? (O0 + (size_t)m * DD + n) : (O1 + (size_t)m * DD + (n - DD));
            } else {
                dst = (n < GG) ? (O0 + (size_t)m * GG + n) : (O1 + (size_t)m * GG + (n - GG));
            }
            *(float4*)dst = v;
        }
    }
}

// ---------------------------------------------------------------------------
// pre-phase scorer (normal cached loads; operands from previous dispatches)
// ---------------------------------------------------------------------------
__device__ __forceinline__ float half_dot(const float* __restrict__ ar,
                                          const float* __restrict__ br,
                                          const float* __restrict__ cb,
                                          const float* __restrict__ cl,
                                          const float* __restrict__ cr,
                                          const float* __restrict__ q, int lane) {
    float part = 0.f;
#pragma unroll
    for (int d = lane; d < DD; d += 128) {
        float gi = ar[d] + br[d] + cb[d];
        float gfl = ar[DD + d] + br[DD + d] + cb[DD + d];
        float gfr = ar[2 * DD + d] + br[2 * DD + d] + cb[2 * DD + d];
        float gu = ar[3 * DD + d] + br[3 * DD + d] + cb[3 * DD + d];
        float go = ar[4 * DD + d] + br[4 * DD + d] + cb[4 * DD + d];
        float nc = cl[d] * sigm(gfl + 1.f) + cr[d] * sigm(gfr + 1.f) + tanhf(gu) * sigm(gi);
        part += sigm(go) * tanhf(nc) * q[d];
    }
#pragma unroll
    for (int off = 32; off; off >>= 1) part += __shfl_down(part, off);
    return part;
}

// ---------------------------------------------------------------------------
// sc1 gate pair for dims d, d+1 (a/b rows coherent; rest cached)
// ---------------------------------------------------------------------------
__device__ __forceinline__ void gate2(const float* ar, const float* br,
                                      const float* __restrict__ cb,
                                      const float* __restrict__ cl,
                                      const float* __restrict__ cr, int d,
                                      float nh[2], float nc[2]) {
    float2 A0 = ldf2(ar + d),          B0 = ldf2(br + d);
    float2 A1 = ldf2(ar + DD + d),     B1 = ldf2(br + DD + d);
    float2 A2 = ldf2(ar + 2 * DD + d), B2 = ldf2(br + 2 * DD + d);
    float2 A3 = ldf2(ar + 3 * DD + d), B3 = ldf2(br + 3 * DD + d);
    float2 A4 = ldf2(ar + 4 * DD + d), B4 = ldf2(br + 4 * DD + d);
    float2 C0 = *(const float2*)(cb + d);
    float2 C1 = *(const float2*)(cb + DD + d);
    float2 C2 = *(const float2*)(cb + 2 * DD + d);
    float2 C3 = *(const float2*)(cb + 3 * DD + d);
    float2 C4 = *(const float2*)(cb + 4 * DD + d);
    float2 CL = *(const float2*)(cl + d);
    float2 CR = *(const float2*)(cr + d);
    float gi0 = A0.x + B0.x + C0.x, gi1 = A0.y + B0.y + C0.y;
    float gfl0 = A1.x + B1.x + C1.x, gfl1 = A1.y + B1.y + C1.y;
    float gfr0 = A2.x + B2.x + C2.x, gfr1 = A2.y + B2.y + C2.y;
    float gu0 = A3.x + B3.x + C3.x, gu1 = A3.y + B3.y + C3.y;
    float go0 = A4.x + B4.x + C4.x, go1 = A4.y + B4.y + C4.y;
    nc[0] = CL.x * sigm(gfl0 + 1.f) + CR.x * sigm(gfr0 + 1.f) + tanhf(gu0) * sigm(gi0);
    nc[1] = CL.y * sigm(gfl1 + 1.f) + CR.y * sigm(gfr1 + 1.f) + tanhf(gu1) * sigm(gi1);
    nh[0] = sigm(go0) * tanhf(nc[0]);
    nh[1] = sigm(go1) * tanhf(nc[1]);
}

// ---------------------------------------------------------------------------
// Persistent kernel: pre-scores + 23 merge steps. R10: grid barriers replaced
// by per-step A-done/B-done dataflow counters; blocks >= NTILES exit early.
// bar layout: step i -> Adone 2 lines @ i*96+{0,16} (target 32 each),
//             Bdone 4 lines @ i*96+{32..80} (target 40 each);
//             pre-done 4 lines @ 2208+{0..48} (target 64 each).
// ---------------------------------------------------------------------------
__global__ __launch_bounds__(256, 2) void loop_k(
    const int* __restrict__ length, float* __restrict__ cbuf, float* __restrict__ acache,
    float* __restrict__ bcache, float* __restrict__ hm, float* __restrict__ hout,
    float* __restrict__ scores_g, int* __restrict__ msel, const float* __restrict__ comp_W,
    const float* __restrict__ compb, const float* __restrict__ q, float* __restrict__ out,
    int* __restrict__ bar) {
    __shared__ float As[128][68];   // phase-B A chunk (k-major)
    __shared__ float Bs[128][36];   // phase-B W chunk
    __shared__ float red_s[4];
    __shared__ float sc_l[32];
    __shared__ int seq_l[32];
    __shared__ int k_sh;
    __shared__ int msel_s[BB];

    const int tid = threadIdx.x;
    const int bid = blockIdx.x;
    const int b = bid;
    const bool amA = bid < BB;
    const int half = tid >> 7;
    const int lane7 = tid & 127;

    int maxlen = 0;
    for (int j = 0; j < BB; ++j) maxlen = max(maxlen, length[j]);
    int lenb = 0, kp = 0;
    if (amA) lenb = length[b];

    // phase-B roles (conflict-free staging maps — verified R9: conflicts = 0)
    const int ar_ = tid & 63, aks = tid >> 6;   // A: row=lane (2-way free), k-slice
    const int wnl = tid & 31, wkg = tid >> 5;   // B: row=lane%32, k-slice
    const float* wrow = nullptr;
    if (bid < NTILES) {
        int n = bid * 32 + wnl;
        wrow = (n < GG) ? (comp_W + (size_t)n * (2 * DD))
                        : (comp_W + (size_t)(n - GG) * (2 * DD) + DD);
    }

    // ---- pre-phase: 23x64 initial candidate scores (512 half-block tasks) ---
    for (int it = 0; it < 3; ++it) {
        int c = it * (2 * NBLK) + bid * 2 + half;
        bool valid = c < BB * NSTEP;
        float w = 0.f;
        if (valid) {
            int cb_ = c / NSTEP, cp = c % NSTEP;
            w = half_dot(acache + (size_t)(cb_ * LL + cp) * GG,
                         bcache + (size_t)(cb_ * LL + cp + 1) * GG, compb,
                         cbuf + (size_t)(cb_ * LL + cp) * DD,
                         cbuf + (size_t)(cb_ * LL + cp + 1) * DD, q, lane7);
        }
        if ((tid & 63) == 0) red_s[tid >> 6] = w;
        __syncthreads();
        if ((tid == 0 || tid == 128) && valid) {
            int base = (tid >> 6);
            stf(&scores_g[c], red_s[base] + red_s[base + 1]);
        }
        __syncthreads();
    }
    arrive_cnt(bar + 2208 + (bid & 3) * BARLINE);
    if (bid >= NTILES) return;  // blocks 160..255: no per-step role

    if (amA) {
        wait_lines<4>(bar + 2208, 64);  // all pre-scores visible
        if (tid < NSTEP) sc_l[tid] = ldf(&scores_g[b * NSTEP + tid]);
        if (tid < LL) seq_l[tid] = tid;
    }
    __syncthreads();

    const int imax = min(NSTEP, maxlen - 1);
    for (int i = 0; i < imax; ++i) {
        int* Ad = bar + i * 96;
        int* Bd = bar + i * 96 + 32;
        // ---------------- phase A (blocks 0..63) ----------------
        if (amA) {
            if (i > 0) wait_lines<4>(bar + (i - 1) * 96 + 32, 40);  // B-done[i-1]
            const int ncand = NSTEP - i;
            if (i > 0 && i < lenb) {
                int p = (tid < 128) ? (kp - 1) : kp;
                bool valid = (p >= 0) && (p < ncand);
                float w = 0.f;
                if (valid) {
                    int sl = seq_l[p], sr = seq_l[p + 1];
                    const float* ar = acache + (size_t)(b * LL + sl) * GG;
                    const float* br = bcache + (size_t)(b * LL + sr) * GG;
                    const float* cl = cbuf + (size_t)(b * LL + sl) * DD;
                    const float* cr = cbuf + (size_t)(b * LL + sr) * DD;
#pragma unroll
                    for (int pass = 0; pass < 2; ++pass) {
                        int d = pass * 256 + lane7 * 2;
                        float nh[2], nc[2];
                        gate2(ar, br, compb, cl, cr, d, nh, nc);
                        float2 Q = *(const float2*)(q + d);
                        w += nh[0] * Q.x + nh[1] * Q.y;
                    }
#pragma unroll
                    for (int off = 32; off; off >>= 1) w += __shfl_down(w, off);
                }
                if ((tid & 63) == 0) red_s[tid >> 6] = w;
                __syncthreads();
                if (tid == 0) {
                    if (kp - 1 >= 0) sc_l[kp - 1] = red_s[0] + red_s[1];
                    if (kp < ncand) sc_l[kp] = red_s[2] + red_s[3];
                }
                __syncthreads();
            }
            if (i + 1 < lenb) {
                if (tid == 0) {
                    const int vmax = lenb - i - 2;
                    int k = 0;
                    float best = sc_l[0];
                    for (int pp = 1; pp <= vmax; ++pp)
                        if (sc_l[pp] > best) { best = sc_l[pp]; k = pp; }
                    k_sh = k;
                }
                __syncthreads();
                const int k = k_sh;
                const int sl = seq_l[k], sr = seq_l[k + 1];
                const float* ar = acache + (size_t)(b * LL + sl) * GG;
                const float* br = bcache + (size_t)(b * LL + sr) * GG;
                const float* cl = cbuf + (size_t)(b * LL + sl) * DD;
                const float* cr = cbuf + (size_t)(b * LL + sr) * DD;
                {
                    const int d = 2 * tid;
                    float nh[2], nc[2];
                    gate2(ar, br, compb, cl, cr, d, nh, nc);
                    *(float2*)(cbuf + (size_t)(b * LL + sl) * DD + d) =
                        make_float2(nc[0], nc[1]);
                    *(float2*)(hout + (size_t)b * DD + d) = make_float2(nh[0], nh[1]);
                    stf2(hm + ((size_t)i * BB + b) * DD + d, nh[0], nh[1]);
                }
                float sv = (tid + 1 < ncand) ? sc_l[tid + 1] : 0.f;
                int qv = (tid + 1 < LL - i) ? seq_l[tid + 1] : 0;
                __syncthreads();
                if (tid >= k + 1 && tid <= ncand - 2) sc_l[tid] = sv;
                if (tid >= k + 1 && tid <= LL - i - 2) seq_l[tid] = qv;
                if (tid == 0) sti(&msel[b], sl);
                kp = k;
            } else {
                const int d = 2 * tid;
                float2 v = *(const float2*)(hout + (size_t)b * DD + d);
                stf2(hm + ((size_t)i * BB + b) * DD + d, v.x, v.y);
            }
            __syncthreads();
            arrive_cnt(Ad + (bid & 1) * BARLINE);
        }
        // ---------------- phase B (blocks 0..159) ----------------
        if (i < imax - 1) {
            float4 rw[4];
#pragma unroll
            for (int j = 0; j < 4; ++j) rw[j] = *(const float4*)(wrow + wkg * 16 + j * 4);
            wait_lines<2>(Ad, 32);
            if (tid < BB) msel_s[tid] = ldi(&msel[tid]);
            __syncthreads();
            {
                const int n0 = bid * 32;
                const int tn = tid & 15, tm = tid >> 4;
                const float* hmi = hm + (size_t)i * BB * DD;
                const float* arow = hmi + (size_t)ar_ * DD;
                float acc[4][2];
#pragma unroll
                for (int y = 0; y < 4; ++y) { acc[y][0] = 0.f; acc[y][1] = 0.f; }
                float4 ra[8];
#pragma unroll
                for (int j = 0; j < 8; ++j) ra[j] = *(const float4*)(arow + aks * 32 + j * 4);
#pragma unroll
                for (int c = 0; c < 4; ++c) {
                    __syncthreads();
#pragma unroll
                    for (int j = 0; j < 8; ++j) {
                        int kl = aks * 32 + j * 4;
                        As[kl + 0][ar_] = ra[j].x;
                        As[kl + 1][ar_] = ra[j].y;
                        As[kl + 2][ar_] = ra[j].z;
                        As[kl + 3][ar_] = ra[j].w;
                    }
#pragma unroll
                    for (int j = 0; j < 4; ++j) {
                        int kl = wkg * 16 + j * 4;
                        Bs[kl + 0][wnl] = rw[j].x;
                        Bs[kl + 1][wnl] = rw[j].y;
                        Bs[kl + 2][wnl] = rw[j].z;
                        Bs[kl + 3][wnl] = rw[j].w;
                    }
                    if (c < 3) {
                        int kb = (c + 1) * 128;
#pragma unroll
                        for (int j = 0; j < 8; ++j)
                            ra[j] = *(const float4*)(arow + kb + aks * 32 + j * 4);
#pragma unroll
                        for (int j = 0; j < 4; ++j)
                            rw[j] = *(const float4*)(wrow + kb + wkg * 16 + j * 4);
                    }
                    __syncthreads();
#pragma unroll 8
                    for (int k = 0; k < 128; ++k) {
                        float4 a = *(const float4*)&As[k][tm * 4];
                        float2 w = *(const float2*)&Bs[k][tn * 2];
                        acc[0][0] += a.x * w.x; acc[0][1] += a.x * w.y;
                        acc[1][0] += a.y * w.x; acc[1][1] += a.y * w.y;
                        acc[2][0] += a.z * w.x; acc[2][1] += a.z * w.y;
                        acc[3][0] += a.w * w.x; acc[3][1] += a.w * w.y;
                    }
                }
                const int n = n0 + tn * 2;
#pragma unroll
                for (int y = 0; y < 4; ++y) {
                    int m = tm * 4 + y;
                    size_t row = (size_t)(m * LL + msel_s[m]);
                    if (n < GG) stf2(acache + row * GG + n, acc[y][0], acc[y][1]);
                    else stf2(bcache + row * GG + (n - GG), acc[y][0], acc[y][1]);
                }
            }
            __syncthreads();
            arrive_cnt(Bd + (bid & 3) * BARLINE);
        }
    }

    if (amA) {
        const int d = 2 * tid;
        *(float2*)(out + (size_t)b * DD + d) = *(const float2*)(hout + (size_t)b * DD + d);
    }
}

// ---------------------------------------------------------------------------
extern "C" void kernel_launch(void* const* d_in, const int* in_sizes, int n_in, void* d_out,
                              int out_size, void* d_ws, size_t ws_size, hipStream_t stream) {
    const float* inp = (const float*)d_in[0];
    const int* length = (const int*)d_in[1];
    const float* word_W = (const float*)d_in[2];
    const float* word_b = (const float*)d_in[3];
    const float* comp_W = (const float*)d_in[4];
    const float* comp_b = (const float*)d_in[5];
    const float* comp_q = (const float*)d_in[6];
    float* out = (float*)d_out;

    float* ws = (float*)d_ws;
    size_t off = 0;
    float* hbuf = ws + off;   off += (size_t)BB * LL * DD;
    float* cbuf = ws + off;   off += (size_t)BB * LL * DD;
    float* acache = ws + off; off += (size_t)BB * LL * GG;
    float* bcache = ws + off; off += (size_t)BB * LL * GG;
    float* hm = ws + off;     off += (size_t)NSTEP * BB * DD;
    float* hout = ws + off;   off += (size_t)BB * DD;
    float* scores = ws + off; off += 2048;
    int* msel = (int*)(ws + off); off += 64;
    int* bar = (int*)(ws + off);  off += 2560;
    (void)ws_size; (void)in_sizes; (void)n_in; (void)out_size;

    init_k<<<1, 256, 0, stream>>>(bar);

    // word projection: h,c = split(inp @ word_W.T + word_b)   (192 blocks)
    gemm64<0><<<dim3(8, 24), 256, 0, stream>>>(inp, word_W, word_b, hbuf, cbuf);

    // a/b caches for all 1536 items                            (960 blocks)
    gemm64<1><<<dim3(40, 24), 256, 0, stream>>>(hbuf, comp_W, nullptr, acache, bcache);

    // persistent kernel: pre-scores + all merge steps
    const int* a0 = length;
    float* a1 = cbuf; float* a2 = acache; float* a3 = bcache; float* a4 = hm;
    float* a5 = hout; float* a6 = scores; int* a7 = msel;
    const float* a8 = comp_W; const float* a9 = comp_b; const float* a10 = comp_q;
    float* a11 = out; int* a12 = bar;
    void* args[] = {&a0, &a1, &a2, &a3, &a4, &a5, &a6, &a7, &a8, &a9, &a10, &a11, &a12};
    hipError_t err = hipLaunchCooperativeKernel(reinterpret_cast<void*>(loop_k), dim3(NBLK),
                                                dim3(256), args, 0, stream);
    (void)err;
}